// Round 3
// baseline (96.166 us; speedup 1.0000x reference)
//
#include <hip/hip_runtime.h>

// n-step return: T=1024, B=4096, gamma=0.99, horizon=16, fp32 in/out.
// G[t,b] = sum_{h=0}^{15} g^h * rm[t+h,b]  (rm = rewards*masks, zero-padded past T)
//        + g^{min(t+16,T)-t} * values[min(t+15,T-1), b]
//
// R2 analysis: scalar staged loads -> ~32us, still latency-limited (256B/wave
// per load, ~8 waves/CU). R3: float4 loads (1KB/wave each), thread owns 4
// columns, CT=8 rows/thread. ~46 independent fat loads/wave => tens of KB in
// flight per CU vs ~9KB needed for 6.3TB/s. Halo re-reads hit L2/L3.

constexpr int   T_DIM  = 1024;
constexpr int   B_DIM  = 4096;
constexpr int   B4     = B_DIM / 4;   // 1024 float4 columns
constexpr int   H      = 16;          // horizon
constexpr int   CT     = 8;           // timesteps per thread
constexpr int   HALO   = H - 1;       // 15
constexpr int   ROWS   = CT + HALO;   // 23 staged rm rows
constexpr float GAMMA  = 0.99f;

constexpr float gpow_c(int n) {
    float g = 1.0f;
    for (int i = 0; i < n; ++i) g *= GAMMA;
    return g;
}
constexpr float G16 = gpow_c(16);

__global__ __launch_bounds__(256, 2)
void NStepReturn_88691074662796_kernel(const float4* __restrict__ rewards,
                                       const float4* __restrict__ values,
                                       const float4* __restrict__ masks,
                                       float4* __restrict__ out)
{
    const int c  = blockIdx.x * 256 + threadIdx.x;        // float4 column (0..1023)
    const int t0 = blockIdx.y * CT;                       // chunk start

    // ---- stage bootstrap values first (fat loads in flight early) ----
    float4 v[CT];
    #pragma unroll
    for (int i = 0; i < CT; ++i) {
        const int vi = min(t0 + i + H - 1, T_DIM - 1);
        v[i] = values[vi * B4 + c];
    }

    // ---- stage rm = rewards*masks for CT+15 rows (independent fat loads) ----
    float4 rm[ROWS];
    #pragma unroll
    for (int i = 0; i < ROWS; ++i) {
        const int t = t0 + i;                             // may exceed T-1 in last chunk
        if (t < T_DIM) {
            const float4 r = rewards[t * B4 + c];
            const float4 m = masks[t * B4 + c];
            rm[i] = make_float4(r.x * m.x, r.y * m.y, r.z * m.z, r.w * m.w);
        } else {
            rm[i] = make_float4(0.f, 0.f, 0.f, 0.f);
        }
    }

    // ---- init: W(t_last) = sum_{h=0}^{15} g^h rm[t_last+h] (Horner) ----
    float4 W = make_float4(0.f, 0.f, 0.f, 0.f);
    #pragma unroll
    for (int h = H - 1; h >= 0; --h) {
        const float4 x = rm[CT - 1 + h];
        W.x = x.x + GAMMA * W.x;
        W.y = x.y + GAMMA * W.y;
        W.z = x.z + GAMMA * W.z;
        W.w = x.w + GAMMA * W.w;
    }

    {   // bootstrap + store for t_last
        const int t = t0 + CT - 1;
        float gb = G16;
        if (t + H > T_DIM) {                              // block-uniform; tail chunks only
            gb = 1.0f;
            for (int k = 0; k < T_DIM - t; ++k) gb *= GAMMA;
        }
        const float4 vv = v[CT - 1];
        out[t * B4 + c] = make_float4(W.x + gb * vv.x, W.y + gb * vv.y,
                                      W.z + gb * vv.z, W.w + gb * vv.w);
    }

    // ---- backward sweep: W(t) = rm[t] + g*W(t+1) - g^16*rm[t+16] ----
    #pragma unroll
    for (int j = CT - 2; j >= 0; --j) {
        const int t = t0 + j;
        const float4 x  = rm[j];
        const float4 x16 = rm[j + H];
        W.x = x.x + GAMMA * W.x - G16 * x16.x;
        W.y = x.y + GAMMA * W.y - G16 * x16.y;
        W.z = x.z + GAMMA * W.z - G16 * x16.z;
        W.w = x.w + GAMMA * W.w - G16 * x16.w;

        float gb = G16;
        if (t + H > T_DIM) {                              // block-uniform; tail chunks only
            gb = 1.0f;
            for (int k = 0; k < T_DIM - t; ++k) gb *= GAMMA;
        }
        const float4 vv = v[j];
        out[t * B4 + c] = make_float4(W.x + gb * vv.x, W.y + gb * vv.y,
                                      W.z + gb * vv.z, W.w + gb * vv.w);
    }
}

extern "C" void kernel_launch(void* const* d_in, const int* in_sizes, int n_in,
                              void* d_out, int out_size, void* d_ws, size_t ws_size,
                              hipStream_t stream) {
    const float4* rewards = (const float4*)d_in[0];
    const float4* values  = (const float4*)d_in[1];
    const float4* masks   = (const float4*)d_in[2];
    float4* out = (float4*)d_out;

    dim3 grid(B4 / 256, T_DIM / CT);   // (4, 128) = 512 blocks
    dim3 block(256);
    NStepReturn_88691074662796_kernel<<<grid, block, 0, stream>>>(rewards, values, masks, out);
}